// Round 7
// baseline (235.649 us; speedup 1.0000x reference)
//
#include <hip/hip_runtime.h>
#include <math.h>

#define HW 262144        // 512*512 elements per batch
#define BPB 32           // blocks per batch
#define CHUNK 8192       // elements per block per input
#define NBLK (64 * BPB)  // 2048 blocks

// clang ext_vector float4: __builtin_nontemporal_load accepts this (the HIP
// struct float4 is rejected — R6 compile failure).
typedef float f4 __attribute__((ext_vector_type(4)));

// Monotonic unsigned mapping of float bits: preserves ordering for all
// finite floats (negatives flipped, positives offset).
__device__ __forceinline__ unsigned int fmono(float f) {
    unsigned int u = __float_as_uint(f);
    return (u & 0x80000000u) ? ~u : (u | 0x80000000u);
}

// Fused: per-block reduce + last-block finalize (device-scope atomic
// counter; canonical threadfence pattern — correct across XCDs, G12/G16).
__global__ __launch_bounds__(256) void loss_kernel(
    const float* __restrict__ pred, const float* __restrict__ label,
    unsigned long long* __restrict__ pblk, unsigned long long* __restrict__ lblk,
    float* __restrict__ sblk, unsigned int* __restrict__ cnt,
    float* __restrict__ out)
{
    const int bi = blockIdx.x;
    const int b = bi >> 5;            // batch
    const int chunk = bi & (BPB - 1);
    const f4* p4 = (const f4*)(pred + (size_t)b * HW) + (size_t)chunk * (CHUNK / 4);
    const f4* l4 = (const f4*)(label + (size_t)b * HW) + (size_t)chunk * (CHUNK / 4);
    const int t = threadIdx.x;
    const int wave = t >> 6, lane = t & 63;
    const unsigned int base = (unsigned int)chunk * CHUNK;

    float sumsq = 0.0f;
    float pmax = -INFINITY, lmax = -INFINITY;
    unsigned int pidx = 0, lidx = 0;

    // Read-once streaming: non-temporal loads (no cache allocation hint).
    // This structure is at the measured ~3.15 TB/s read ceiling (R1-R5:
    // five staging variants all pinned at 42-45 us) — keep it simple.
#pragma unroll
    for (int i = 0; i < 8; ++i) {
        const f4 p = __builtin_nontemporal_load(p4 + i * 256 + t);
        const f4 l = __builtin_nontemporal_load(l4 + i * 256 + t);
        const unsigned int e = base + ((unsigned int)(i * 256 + t)) * 4u;
        float d;
        d = p[0] - l[0]; sumsq += d * d;
        d = p[1] - l[1]; sumsq += d * d;
        d = p[2] - l[2]; sumsq += d * d;
        d = p[3] - l[3]; sumsq += d * d;
        // strict > keeps the first (lowest-index) occurrence within a thread
        if (p[0] > pmax) { pmax = p[0]; pidx = e;      }
        if (p[1] > pmax) { pmax = p[1]; pidx = e + 1u; }
        if (p[2] > pmax) { pmax = p[2]; pidx = e + 2u; }
        if (p[3] > pmax) { pmax = p[3]; pidx = e + 3u; }
        if (l[0] > lmax) { lmax = l[0]; lidx = e;      }
        if (l[1] > lmax) { lmax = l[1]; lidx = e + 1u; }
        if (l[2] > lmax) { lmax = l[2]; lidx = e + 2u; }
        if (l[3] > lmax) { lmax = l[3]; lidx = e + 3u; }
    }

    // pack: high 32 = monotonic value bits, low 32 = ~index so that on value
    // tie the LOWER index wins under unsigned max (matches jnp.argmax).
    unsigned long long ppk = ((unsigned long long)fmono(pmax) << 32) | (unsigned long long)(0xFFFFFFFFu - pidx);
    unsigned long long lpk = ((unsigned long long)fmono(lmax) << 32) | (unsigned long long)(0xFFFFFFFFu - lidx);

    // wave(64) shuffle reduction
    for (int off = 32; off > 0; off >>= 1) {
        sumsq += __shfl_down(sumsq, off);
        unsigned long long o;
        o = __shfl_down(ppk, off); if (o > ppk) ppk = o;
        o = __shfl_down(lpk, off); if (o > lpk) lpk = o;
    }

    __shared__ float s_sum[4];
    __shared__ unsigned long long s_pp[4], s_lp[4];
    __shared__ unsigned int s_last;
    if (lane == 0) { s_sum[wave] = sumsq; s_pp[wave] = ppk; s_lp[wave] = lpk; }
    __syncthreads();
    if (t == 0) {
        float s = s_sum[0] + s_sum[1] + s_sum[2] + s_sum[3];
        unsigned long long Pk = s_pp[0], Lk = s_lp[0];
#pragma unroll
        for (int i = 1; i < 4; ++i) {
            if (s_pp[i] > Pk) Pk = s_pp[i];
            if (s_lp[i] > Lk) Lk = s_lp[i];
        }
        pblk[bi] = Pk;
        lblk[bi] = Lk;
        sblk[bi] = s;
        __threadfence();                       // release partials (device scope)
        s_last = (atomicAdd(cnt, 1u) == NBLK - 1u);
    }
    __syncthreads();
    if (!s_last) return;

    // ---- last block: final reduction over 2048 partials (L2-hot, ~40 KB) ----
    __threadfence();                           // acquire partials

    // global mse: 8 partials per thread
    float s = 0.0f;
#pragma unroll
    for (int k = 0; k < 8; ++k) s = s + sblk[t + k * 256];
    for (int off = 32; off > 0; off >>= 1) s += __shfl_down(s, off);
    __shared__ float ss[4];
    if (lane == 0) ss[wave] = s;

    // per-batch argmax: batch = t>>2, j = t&3; each thread covers 8 chunks
    const int batch = t >> 2, j = t & 3;
    unsigned long long Pv = 0ull, Lv = 0ull, o;
#pragma unroll
    for (int k = 0; k < 8; ++k) {
        o = pblk[batch * 32 + j + k * 4]; if (o > Pv) Pv = o;
        o = lblk[batch * 32 + j + k * 4]; if (o > Lv) Lv = o;
    }
    for (int off = 2; off > 0; off >>= 1) {
        o = __shfl_down(Pv, off, 4); if (o > Pv) Pv = o;
        o = __shfl_down(Lv, off, 4); if (o > Lv) Lv = o;
    }
    __shared__ float dd[64];
    if (j == 0) {
        const unsigned int ip = 0xFFFFFFFFu - (unsigned int)(Pv & 0xFFFFFFFFull);
        const unsigned int il = 0xFFFFFFFFu - (unsigned int)(Lv & 0xFFFFFFFFull);
        const float rp = (float)(ip >> 9), cp = (float)(ip & 511u);
        const float rl = (float)(il >> 9), cl = (float)(il & 511u);
        dd[batch] = (rp - rl) * (rp - rl) + (cp - cl) * (cp - cl);
    }
    __syncthreads();
    if (t < 64) {
        float d = dd[t];
        for (int off = 32; off > 0; off >>= 1) d += __shfl_down(d, off);
        if (t == 0) {
            const float m = ss[0] + ss[1] + ss[2] + ss[3];
            const float alpha = (d != 0.0f) ? (m / d) : 1.0f;
            out[0] = (m + 0.25f * alpha * d) / 64.0f;
        }
    }
}

extern "C" void kernel_launch(void* const* d_in, const int* in_sizes, int n_in,
                              void* d_out, int out_size, void* d_ws, size_t ws_size,
                              hipStream_t stream) {
    const float* pred  = (const float*)d_in[0];
    const float* label = (const float*)d_in[1];
    float* out = (float*)d_out;

    unsigned long long* pblk = (unsigned long long*)d_ws;  // 2048 packed pred argmax
    unsigned long long* lblk = pblk + NBLK;                // 2048 packed label argmax
    float* sblk = (float*)(lblk + NBLK);                   // 2048 mse partials
    unsigned int* cnt = (unsigned int*)(sblk + NBLK);      // completion counter

    // only the counter needs zero-init (ws is poisoned 0xAA each launch)
    (void)hipMemsetAsync(cnt, 0, sizeof(unsigned int), stream);

    loss_kernel<<<dim3(NBLK), dim3(256), 0, stream>>>(pred, label, pblk, lblk, sblk, cnt, out);
}

// Round 8
// 143.625 us; speedup vs baseline: 1.6407x; 1.6407x over previous
//
#include <hip/hip_runtime.h>
#include <math.h>

#define HW 262144   // 512*512 elements per batch
#define BPB 32      // blocks per batch
#define CHUNK 8192  // elements per block; per thread 32 elements = 8 float4 per input
#define NBLK (64 * BPB)  // 2048 blocks

// Monotonic unsigned mapping of float bits: preserves ordering for all
// finite floats (negatives flipped, positives offset).
__device__ __forceinline__ unsigned int fmono(float f) {
    unsigned int u = __float_as_uint(f);
    return (u & 0x80000000u) ? ~u : (u | 0x80000000u);
}

// R3/R4 best-known structure. R1-R5 established the ~3.15 TB/s blended read
// ceiling for this pattern (five staging variants all 42-45 us); R7 showed
// last-block fusion (per-block device fences) is a 3x regression. Keep the
// simple two-dispatch form: streaming reduce + tiny finalize.
__global__ __launch_bounds__(256) void reduce_kernel(
    const float* __restrict__ pred, const float* __restrict__ label,
    unsigned long long* __restrict__ pblk, unsigned long long* __restrict__ lblk,
    float* __restrict__ sblk)
{
    const int bi = blockIdx.x;
    const int b = bi >> 5;            // batch
    const int chunk = bi & (BPB - 1);
    const float4* p4 = (const float4*)(pred + (size_t)b * HW) + (size_t)chunk * (CHUNK / 4);
    const float4* l4 = (const float4*)(label + (size_t)b * HW) + (size_t)chunk * (CHUNK / 4);
    const int t = threadIdx.x;
    const unsigned int base = (unsigned int)chunk * CHUNK;

    float sumsq = 0.0f;
    float pmax = -INFINITY, lmax = -INFINITY;
    unsigned int pidx = 0, lidx = 0;

#pragma unroll
    for (int i = 0; i < 8; ++i) {
        const float4 p = p4[i * 256 + t];
        const float4 l = l4[i * 256 + t];
        const unsigned int e = base + ((unsigned int)(i * 256 + t)) * 4u;
        float d;
        d = p.x - l.x; sumsq += d * d;
        d = p.y - l.y; sumsq += d * d;
        d = p.z - l.z; sumsq += d * d;
        d = p.w - l.w; sumsq += d * d;
        // strict > keeps the first (lowest-index) occurrence within a thread
        if (p.x > pmax) { pmax = p.x; pidx = e;      }
        if (p.y > pmax) { pmax = p.y; pidx = e + 1u; }
        if (p.z > pmax) { pmax = p.z; pidx = e + 2u; }
        if (p.w > pmax) { pmax = p.w; pidx = e + 3u; }
        if (l.x > lmax) { lmax = l.x; lidx = e;      }
        if (l.y > lmax) { lmax = l.y; lidx = e + 1u; }
        if (l.z > lmax) { lmax = l.z; lidx = e + 2u; }
        if (l.w > lmax) { lmax = l.w; lidx = e + 3u; }
    }

    // pack: high 32 = monotonic value bits, low 32 = ~index so that on value
    // tie the LOWER index wins under unsigned max (matches jnp.argmax).
    unsigned long long ppk = ((unsigned long long)fmono(pmax) << 32) | (unsigned long long)(0xFFFFFFFFu - pidx);
    unsigned long long lpk = ((unsigned long long)fmono(lmax) << 32) | (unsigned long long)(0xFFFFFFFFu - lidx);

    // wave(64) shuffle reduction
    for (int off = 32; off > 0; off >>= 1) {
        sumsq += __shfl_down(sumsq, off);
        unsigned long long o;
        o = __shfl_down(ppk, off); if (o > ppk) ppk = o;
        o = __shfl_down(lpk, off); if (o > lpk) lpk = o;
    }

    __shared__ float s_sum[4];
    __shared__ unsigned long long s_pp[4], s_lp[4];
    const int wave = t >> 6, lane = t & 63;
    if (lane == 0) { s_sum[wave] = sumsq; s_pp[wave] = ppk; s_lp[wave] = lpk; }
    __syncthreads();
    if (t == 0) {
        float s = s_sum[0] + s_sum[1] + s_sum[2] + s_sum[3];
        unsigned long long Pk = s_pp[0], Lk = s_lp[0];
#pragma unroll
        for (int i = 1; i < 4; ++i) {
            if (s_pp[i] > Pk) Pk = s_pp[i];
            if (s_lp[i] > Lk) Lk = s_lp[i];
        }
        // Atomic-free: every block writes its own slot (no memset, no fences).
        pblk[bi] = Pk;
        lblk[bi] = Lk;
        sblk[bi] = s;
    }
}

// One block, 1024 threads: reduces 2048 per-block partials.
__global__ __launch_bounds__(1024) void finalize_kernel(
    const unsigned long long* __restrict__ pblk,
    const unsigned long long* __restrict__ lblk,
    const float* __restrict__ sblk,
    float* __restrict__ out)
{
    const int t = threadIdx.x;  // 0..1023

    // global mse: sum of all 2048 partials
    float s = sblk[t] + sblk[t + 1024];
    for (int off = 32; off > 0; off >>= 1) s += __shfl_down(s, off);
    __shared__ float ss[16];
    const int wave = t >> 6;
    if ((t & 63) == 0) ss[wave] = s;

    // per-batch argmax over 32 chunk partials: batch = t>>4, j = t&15
    const int batch = t >> 4, j = t & 15;
    unsigned long long Pv = pblk[batch * 32 + j];
    unsigned long long o  = pblk[batch * 32 + j + 16];
    if (o > Pv) Pv = o;
    unsigned long long Lv = lblk[batch * 32 + j];
    o = lblk[batch * 32 + j + 16];
    if (o > Lv) Lv = o;
    for (int off = 8; off > 0; off >>= 1) {
        o = __shfl_down(Pv, off, 16); if (o > Pv) Pv = o;
        o = __shfl_down(Lv, off, 16); if (o > Lv) Lv = o;
    }
    __shared__ float dd[64];
    if (j == 0) {
        const unsigned int ip = 0xFFFFFFFFu - (unsigned int)(Pv & 0xFFFFFFFFull);
        const unsigned int il = 0xFFFFFFFFu - (unsigned int)(Lv & 0xFFFFFFFFull);
        const float rp = (float)(ip >> 9), cp = (float)(ip & 511u);
        const float rl = (float)(il >> 9), cl = (float)(il & 511u);
        dd[batch] = (rp - rl) * (rp - rl) + (cp - cl) * (cp - cl);
    }
    __syncthreads();
    if (t < 64) {
        float d = dd[t];
        for (int off = 32; off > 0; off >>= 1) d += __shfl_down(d, off);
        if (t == 0) {
            float m = 0.0f;
#pragma unroll
            for (int i = 0; i < 16; ++i) m += ss[i];
            const float alpha = (d != 0.0f) ? (m / d) : 1.0f;
            out[0] = (m + 0.25f * alpha * d) / 64.0f;
        }
    }
}

extern "C" void kernel_launch(void* const* d_in, const int* in_sizes, int n_in,
                              void* d_out, int out_size, void* d_ws, size_t ws_size,
                              hipStream_t stream) {
    const float* pred  = (const float*)d_in[0];
    const float* label = (const float*)d_in[1];
    float* out = (float*)d_out;

    unsigned long long* pblk = (unsigned long long*)d_ws;  // 2048 packed pred argmax
    unsigned long long* lblk = pblk + NBLK;                // 2048 packed label argmax
    float* sblk = (float*)(lblk + NBLK);                   // 2048 mse partials

    reduce_kernel<<<dim3(NBLK), dim3(256), 0, stream>>>(pred, label, pblk, lblk, sblk);
    finalize_kernel<<<dim3(1), dim3(1024), 0, stream>>>(pblk, lblk, sblk, out);
}

// Round 9
// 142.293 us; speedup vs baseline: 1.6561x; 1.0094x over previous
//
#include <hip/hip_runtime.h>
#include <math.h>

#define HW 262144        // 512*512 elements per batch
#define BPB 32           // blocks per batch
#define CHUNK 8192       // elements per block per input; 32KB+32KB = 64KB LDS
#define NBLK (64 * BPB)  // 2048 blocks

// Fire-and-forget global->LDS DMA, 16B per lane per instruction (1KB/wave).
// LDS dest = wave-uniform base + lane*16 (m104/m108); gaddr is per-lane.
// Usage validated on-HW in R5.
#define GL2LDS(g, l)                                                      \
    __builtin_amdgcn_global_load_lds(                                     \
        (const __attribute__((address_space(1))) void*)(g),               \
        (__attribute__((address_space(3))) void*)(l), 16, 0, 0)

// Monotonic unsigned mapping of float bits: preserves ordering for all
// finite floats (negatives flipped, positives offset).
__device__ __forceinline__ unsigned int fmono(float f) {
    unsigned int u = __float_as_uint(f);
    return (u & 0x80000000u) ? ~u : (u | 0x80000000u);
}

// R9 experiment: ONE stream per wave. R1-R8's five pinned variants (42-45us,
// 3.15 TB/s delivered) all interleaved pred+label per wave; m146's RMSNorm
// (single-stream, 16B/lane) reaches 4.89 TB/s. Waves 0-1 DMA pred, waves
// 2-3 DMA label; compute phase (from LDS) is identical to R5's verified one.
__global__ __launch_bounds__(256) void reduce_kernel(
    const float* __restrict__ pred, const float* __restrict__ label,
    unsigned long long* __restrict__ pblk, unsigned long long* __restrict__ lblk,
    float* __restrict__ sblk)
{
    __shared__ __align__(16) float lds[2 * CHUNK];   // [0,8192)=pred, [8192,16384)=label

    const int bi = blockIdx.x;
    const int b = bi >> 5;            // batch
    const int chunk = bi & (BPB - 1);
    const float* pbase = pred  + (size_t)b * HW + (size_t)chunk * CHUNK;
    const float* lbase = label + (size_t)b * HW + (size_t)chunk * CHUNK;
    const int t = threadIdx.x;
    const int wave = t >> 6, lane = t & 63;
    const unsigned int base = (unsigned int)chunk * CHUNK;

    // Staging: wave w handles ONE contiguous 16KB single-stream run:
    //   w=0: pred[0,4096)   w=1: pred[4096,8192)
    //   w=2: label[0,4096)  w=3: label[4096,8192)
    {
        const int half = wave & 1;
        const float* g = ((wave < 2) ? pbase : lbase) + half * 4096 + lane * 4;
        float* l = lds + ((wave < 2) ? 0 : CHUNK) + half * 4096;   // wave-uniform
#pragma unroll
        for (int j = 0; j < 16; ++j) {
            GL2LDS(g + j * 256, l + j * 256);
        }
    }
    __syncthreads();   // compiler emits s_waitcnt vmcnt(0) before s_barrier

    const float4* lp4 = (const float4*)lds;
    const float4* ll4 = (const float4*)(lds + CHUNK);

    float sumsq = 0.0f;
    float pmax = -INFINITY, lmax = -INFINITY;
    unsigned int pidx = 0, lidx = 0;

#pragma unroll
    for (int i = 0; i < 8; ++i) {
        const float4 p = lp4[i * 256 + t];
        const float4 l = ll4[i * 256 + t];
        const unsigned int e = base + ((unsigned int)(i * 256 + t)) * 4u;
        float d;
        d = p.x - l.x; sumsq += d * d;
        d = p.y - l.y; sumsq += d * d;
        d = p.z - l.z; sumsq += d * d;
        d = p.w - l.w; sumsq += d * d;
        // strict > keeps the first (lowest-index) occurrence within a thread
        if (p.x > pmax) { pmax = p.x; pidx = e;      }
        if (p.y > pmax) { pmax = p.y; pidx = e + 1u; }
        if (p.z > pmax) { pmax = p.z; pidx = e + 2u; }
        if (p.w > pmax) { pmax = p.w; pidx = e + 3u; }
        if (l.x > lmax) { lmax = l.x; lidx = e;      }
        if (l.y > lmax) { lmax = l.y; lidx = e + 1u; }
        if (l.z > lmax) { lmax = l.z; lidx = e + 2u; }
        if (l.w > lmax) { lmax = l.w; lidx = e + 3u; }
    }

    // pack: high 32 = monotonic value bits, low 32 = ~index so that on value
    // tie the LOWER index wins under unsigned max (matches jnp.argmax).
    unsigned long long ppk = ((unsigned long long)fmono(pmax) << 32) | (unsigned long long)(0xFFFFFFFFu - pidx);
    unsigned long long lpk = ((unsigned long long)fmono(lmax) << 32) | (unsigned long long)(0xFFFFFFFFu - lidx);

    // wave(64) shuffle reduction
    for (int off = 32; off > 0; off >>= 1) {
        sumsq += __shfl_down(sumsq, off);
        unsigned long long o;
        o = __shfl_down(ppk, off); if (o > ppk) ppk = o;
        o = __shfl_down(lpk, off); if (o > lpk) lpk = o;
    }

    __shared__ float s_sum[4];
    __shared__ unsigned long long s_pp[4], s_lp[4];
    if (lane == 0) { s_sum[wave] = sumsq; s_pp[wave] = ppk; s_lp[wave] = lpk; }
    __syncthreads();
    if (t == 0) {
        float s = s_sum[0] + s_sum[1] + s_sum[2] + s_sum[3];
        unsigned long long Pk = s_pp[0], Lk = s_lp[0];
#pragma unroll
        for (int i = 1; i < 4; ++i) {
            if (s_pp[i] > Pk) Pk = s_pp[i];
            if (s_lp[i] > Lk) Lk = s_lp[i];
        }
        // Atomic-free: every block writes its own slot (no memset, no fences).
        pblk[bi] = Pk;
        lblk[bi] = Lk;
        sblk[bi] = s;
    }
}

// One block, 1024 threads: reduces 2048 per-block partials.
__global__ __launch_bounds__(1024) void finalize_kernel(
    const unsigned long long* __restrict__ pblk,
    const unsigned long long* __restrict__ lblk,
    const float* __restrict__ sblk,
    float* __restrict__ out)
{
    const int t = threadIdx.x;  // 0..1023

    // global mse: sum of all 2048 partials
    float s = sblk[t] + sblk[t + 1024];
    for (int off = 32; off > 0; off >>= 1) s += __shfl_down(s, off);
    __shared__ float ss[16];
    const int wave = t >> 6;
    if ((t & 63) == 0) ss[wave] = s;

    // per-batch argmax over 32 chunk partials: batch = t>>4, j = t&15
    const int batch = t >> 4, j = t & 15;
    unsigned long long Pv = pblk[batch * 32 + j];
    unsigned long long o  = pblk[batch * 32 + j + 16];
    if (o > Pv) Pv = o;
    unsigned long long Lv = lblk[batch * 32 + j];
    o = lblk[batch * 32 + j + 16];
    if (o > Lv) Lv = o;
    for (int off = 8; off > 0; off >>= 1) {
        o = __shfl_down(Pv, off, 16); if (o > Pv) Pv = o;
        o = __shfl_down(Lv, off, 16); if (o > Lv) Lv = o;
    }
    __shared__ float dd[64];
    if (j == 0) {
        const unsigned int ip = 0xFFFFFFFFu - (unsigned int)(Pv & 0xFFFFFFFFull);
        const unsigned int il = 0xFFFFFFFFu - (unsigned int)(Lv & 0xFFFFFFFFull);
        const float rp = (float)(ip >> 9), cp = (float)(ip & 511u);
        const float rl = (float)(il >> 9), cl = (float)(il & 511u);
        dd[batch] = (rp - rl) * (rp - rl) + (cp - cl) * (cp - cl);
    }
    __syncthreads();
    if (t < 64) {
        float d = dd[t];
        for (int off = 32; off > 0; off >>= 1) d += __shfl_down(d, off);
        if (t == 0) {
            float m = 0.0f;
#pragma unroll
            for (int i = 0; i < 16; ++i) m += ss[i];
            const float alpha = (d != 0.0f) ? (m / d) : 1.0f;
            out[0] = (m + 0.25f * alpha * d) / 64.0f;
        }
    }
}

extern "C" void kernel_launch(void* const* d_in, const int* in_sizes, int n_in,
                              void* d_out, int out_size, void* d_ws, size_t ws_size,
                              hipStream_t stream) {
    const float* pred  = (const float*)d_in[0];
    const float* label = (const float*)d_in[1];
    float* out = (float*)d_out;

    unsigned long long* pblk = (unsigned long long*)d_ws;  // 2048 packed pred argmax
    unsigned long long* lblk = pblk + NBLK;                // 2048 packed label argmax
    float* sblk = (float*)(lblk + NBLK);                   // 2048 mse partials

    reduce_kernel<<<dim3(NBLK), dim3(256), 0, stream>>>(pred, label, pblk, lblk, sblk);
    finalize_kernel<<<dim3(1), dim3(1024), 0, stream>>>(pblk, lblk, sblk, out);
}